// Round 1
// baseline (146.399 us; speedup 1.0000x reference)
//
#include <hip/hip_runtime.h>
#include <hip/hip_bf16.h>

// out[i,j] = alpha[i] * alpha[j] * A_hat[i,j]   (N x N, fp32)
// Memory-bound elementwise: vectorized float4 loads/stores, 16 B per lane.

__global__ __launch_bounds__(256) void stable_factor_kernel(
    const float* __restrict__ A,
    const float* __restrict__ alpha,
    float* __restrict__ out,
    int N) {
    const int nvec = N >> 2;                        // float4s per row (2500)
    const int col4 = blockIdx.x * blockDim.x + threadIdx.x;
    const int row  = blockIdx.y;
    if (col4 >= nvec) return;

    const float ai = alpha[row];                    // wave-uniform-ish, cached
    const size_t row_off = (size_t)row * (size_t)N;

    const float4* __restrict__ A4  = reinterpret_cast<const float4*>(A + row_off);
    const float4* __restrict__ al4 = reinterpret_cast<const float4*>(alpha);
    float4* __restrict__ O4        = reinterpret_cast<float4*>(out + row_off);

    float4 a = A4[col4];
    float4 b = al4[col4];

    float4 o;
    o.x = ai * b.x * a.x;
    o.y = ai * b.y * a.y;
    o.z = ai * b.z * a.z;
    o.w = ai * b.w * a.w;

    O4[col4] = o;
}

extern "C" void kernel_launch(void* const* d_in, const int* in_sizes, int n_in,
                              void* d_out, int out_size, void* d_ws, size_t ws_size,
                              hipStream_t stream) {
    const float* A     = (const float*)d_in[0];   // A_hat, N*N fp32
    const float* alpha = (const float*)d_in[1];   // alpha, N fp32
    float* out         = (float*)d_out;

    const int N = in_sizes[1];                    // 10000
    const int nvec = N >> 2;                      // 2500 float4 per row

    dim3 block(256, 1, 1);
    dim3 grid((nvec + 255) / 256, N, 1);          // 10 x 10000 blocks
    stable_factor_kernel<<<grid, block, 0, stream>>>(A, alpha, out, N);
}